// Round 1
// baseline (612.595 us; speedup 1.0000x reference)
//
#include <hip/hip_runtime.h>
#include <stdint.h>
#include <stddef.h>

typedef __bf16 bf16_t;
typedef __bf16 bf16x8 __attribute__((ext_vector_type(8)));
typedef __bf16 bf16x4 __attribute__((ext_vector_type(4)));
typedef float  f32x4  __attribute__((ext_vector_type(4)));

// ---------------------------------------------------------------------------
// Kernel 1: per-block partial sums of |W|  (W is 1024x1024 fp32 = 1M elems)
// 256 blocks x 256 threads, each thread reads 4 float4 (16 floats).
// ---------------------------------------------------------------------------
__global__ __launch_bounds__(256)
void k_abssum(const float* __restrict__ W, float* __restrict__ partials) {
    const int t = threadIdx.x;
    const int b = blockIdx.x;
    const f32x4* W4 = reinterpret_cast<const f32x4*>(W);
    float s = 0.f;
    const int base = b * 1024 + t;           // float4 index
#pragma unroll
    for (int i = 0; i < 4; ++i) {
        f32x4 v = W4[base + i * 256];
        s += fabsf(v[0]) + fabsf(v[1]) + fabsf(v[2]) + fabsf(v[3]);
    }
#pragma unroll
    for (int off = 32; off > 0; off >>= 1) s += __shfl_down(s, off);
    __shared__ float red[4];
    if ((t & 63) == 0) red[t >> 6] = s;
    __syncthreads();
    if (t == 0) partials[b] = red[0] + red[1] + red[2] + red[3];
}

// ---------------------------------------------------------------------------
// Kernel 2: combine partials -> scale; ternarize W to bf16 {-1,0,1}.
// 1024 blocks x 256 threads, each thread handles one float4 of W.
// Every block redundantly reduces the 256 partials (deterministic, cheap).
// ---------------------------------------------------------------------------
__global__ __launch_bounds__(256)
void k_ternarize(const float* __restrict__ W, const float* __restrict__ partials,
                 bf16_t* __restrict__ T, float* __restrict__ scale_out) {
    const int t = threadIdx.x;
    const int b = blockIdx.x;
    float s = partials[t];
#pragma unroll
    for (int off = 32; off > 0; off >>= 1) s += __shfl_down(s, off);
    __shared__ float red[4];
    if ((t & 63) == 0) red[t >> 6] = s;
    __syncthreads();
    const float total = red[0] + red[1] + red[2] + red[3];
    const float scale = total * (1.0f / 1048576.0f);
    const float inv   = 1.0f / fmaxf(scale, 1e-8f);

    const int idx = b * 256 + t;             // float4 index, 262144 total
    f32x4 w = reinterpret_cast<const f32x4*>(W)[idx];
    bf16x4 q;
#pragma unroll
    for (int j = 0; j < 4; ++j) {
        float qn = rintf(w[j] * inv);
        qn = fminf(1.f, fmaxf(-1.f, qn));
        q[j] = (bf16_t)qn;
    }
    reinterpret_cast<bf16x4*>(T)[idx] = q;
    if (b == 0 && t == 0) scale_out[0] = scale;
}

// ---------------------------------------------------------------------------
// Kernel 3: GEMM  out[m][n] = scale * sum_k x[m][k]*t[n][k] + bias[n]
// M=65536, N=1024, K=1024.  BM=BN=128, BK=32, 256 threads (4 waves, 2x2).
// A (x, fp32) reg-staged with fused bf16 convert into padded LDS (+16B/row).
// B (t, bf16) staged via global_load_lds width-16 (linear LDS).
// mfma_f32_16x16x32_bf16, 4x4 fragments per wave (64x64 per wave).
// ---------------------------------------------------------------------------
__global__ __launch_bounds__(256)
void k_gemm(const float* __restrict__ X, const bf16_t* __restrict__ T,
            const float* __restrict__ bias, const float* __restrict__ scale_p,
            float* __restrict__ Out) {
    __shared__ bf16_t As[128][40];   // padded: 80 B rows -> conflict-light reads
    __shared__ bf16_t Bs[128][32];   // linear: global_load_lds destination

    const int tid  = threadIdx.x;
    const int lane = tid & 63;
    const int w    = tid >> 6;       // wave 0..3
    const int wr   = w >> 1;         // wave row (2)
    const int wc   = w & 1;          // wave col (2)

    // XCD-aware bijective swizzle: 4096 blocks, 8 XCDs, 512 per XCD.
    // Within an XCD, the 8 blocks sharing an A-panel are consecutive.
    const int bid = blockIdx.x;
    const int sid = (bid & 7) * 512 + (bid >> 3);
    const int bn  = sid & 7;         // 0..7
    const int bm  = sid >> 3;        // 0..511
    const int row0 = bm * 128;
    const int col0 = bn * 128;

    // A staging: thread covers rows (tid>>2) and (tid>>2)+64, 8 floats at col (tid&3)*8
    const int ar = tid >> 2;
    const int ac = (tid & 3) * 8;
    const float* xA0 = X + (size_t)(row0 + ar) * 1024 + ac;
    const float* xA1 = X + (size_t)(row0 + ar + 64) * 1024 + ac;

    // B staging (global_load_lds): wave w covers rows [w*32, w*32+32)
    const int brow = w * 32 + (lane >> 2);
    const int bcol = (lane & 3) * 8;
    const bf16_t* gB = T + (size_t)(col0 + brow) * 1024 + bcol;

    f32x4 acc[4][4];
    {
        f32x4 z = {0.f, 0.f, 0.f, 0.f};
#pragma unroll
        for (int i = 0; i < 4; ++i)
#pragma unroll
            for (int j = 0; j < 4; ++j) acc[i][j] = z;
    }

    f32x4 a_reg[2][2];
#define LOAD_A(kt)                                                             \
    {                                                                          \
        const float* p0 = xA0 + (kt) * 32;                                     \
        const float* p1 = xA1 + (kt) * 32;                                     \
        a_reg[0][0] = *(const f32x4*)(p0);                                     \
        a_reg[0][1] = *(const f32x4*)(p0 + 4);                                 \
        a_reg[1][0] = *(const f32x4*)(p1);                                     \
        a_reg[1][1] = *(const f32x4*)(p1 + 4);                                 \
    }

    LOAD_A(0);

    const int g16 = (lane >> 4) * 8;   // k offset within BK (elems)
    const int rl  = lane & 15;

    for (int kt = 0; kt < 32; ++kt) {
        __syncthreads();   // previous tile's compute done
        // --- stage A: convert fp32 -> bf16, ds_write_b128 into padded rows
#pragma unroll
        for (int h = 0; h < 2; ++h) {
            bf16x8 v;
#pragma unroll
            for (int j = 0; j < 4; ++j) {
                v[j]     = (bf16_t)a_reg[h][0][j];
                v[4 + j] = (bf16_t)a_reg[h][1][j];
            }
            *reinterpret_cast<bf16x8*>(&As[ar + h * 64][ac]) = v;
        }
        // --- stage B: 2 x global_load_lds (16 rows / wave / issue)
        {
            const bf16_t* g0 = gB + kt * 32;
            __builtin_amdgcn_global_load_lds(
                (const __attribute__((address_space(1))) void*)g0,
                (__attribute__((address_space(3))) void*)&Bs[w * 32][0], 16, 0, 0);
            __builtin_amdgcn_global_load_lds(
                (const __attribute__((address_space(1))) void*)(g0 + 16 * 1024),
                (__attribute__((address_space(3))) void*)&Bs[w * 32 + 16][0], 16, 0, 0);
        }
        __syncthreads();   // tile ready (vmcnt+lgkmcnt drained by compiler)

        // prefetch next A tile's globals; they drain at next top barrier
        if (kt + 1 < 32) LOAD_A(kt + 1);

        // --- compute: 8 x ds_read_b128 + 16 x MFMA per wave
        bf16x8 af[4], bfr[4];
#pragma unroll
        for (int mi = 0; mi < 4; ++mi)
            af[mi] = *reinterpret_cast<const bf16x8*>(&As[wr * 64 + mi * 16 + rl][g16]);
#pragma unroll
        for (int ni = 0; ni < 4; ++ni)
            bfr[ni] = *reinterpret_cast<const bf16x8*>(&Bs[wc * 64 + ni * 16 + rl][g16]);
#pragma unroll
        for (int mi = 0; mi < 4; ++mi)
#pragma unroll
            for (int ni = 0; ni < 4; ++ni)
                acc[mi][ni] = __builtin_amdgcn_mfma_f32_16x16x32_bf16(
                    af[mi], bfr[ni], acc[mi][ni], 0, 0, 0);
    }

    // --- epilogue: out = acc*scale + bias
    const float scale = scale_p[0];
    float bv[4];
#pragma unroll
    for (int ni = 0; ni < 4; ++ni)
        bv[ni] = bias[col0 + wc * 64 + ni * 16 + rl];
#pragma unroll
    for (int mi = 0; mi < 4; ++mi) {
        const int gm0 = row0 + wr * 64 + mi * 16 + (lane >> 4) * 4;
#pragma unroll
        for (int ni = 0; ni < 4; ++ni) {
            const int gn = col0 + wc * 64 + ni * 16 + rl;
#pragma unroll
            for (int j = 0; j < 4; ++j)
                Out[(size_t)(gm0 + j) * 1024 + gn] = acc[mi][ni][j] * scale + bv[ni];
        }
    }
#undef LOAD_A
}

// ---------------------------------------------------------------------------
extern "C" void kernel_launch(void* const* d_in, const int* in_sizes, int n_in,
                              void* d_out, int out_size, void* d_ws, size_t ws_size,
                              hipStream_t stream) {
    const float* x    = (const float*)d_in[0];   // [8,8192,1024] fp32
    const float* W    = (const float*)d_in[1];   // [1024,1024]   fp32
    const float* bias = (const float*)d_in[2];   // [1024]        fp32
    float* out = (float*)d_out;

    float*  ws_part  = (float*)d_ws;             // 256 floats
    float*  ws_scale = ws_part + 256;            // 1 float
    bf16_t* ws_T     = (bf16_t*)(ws_part + 512); // 1M bf16 = 2 MB (16B aligned)

    hipLaunchKernelGGL(k_abssum,    dim3(256),  dim3(256), 0, stream, W, ws_part);
    hipLaunchKernelGGL(k_ternarize, dim3(1024), dim3(256), 0, stream, W, ws_part, ws_T, ws_scale);
    hipLaunchKernelGGL(k_gemm,      dim3(4096), dim3(256), 0, stream, x, ws_T, bias, ws_scale, out);
}

// Round 5
// 576.070 us; speedup vs baseline: 1.0634x; 1.0634x over previous
//
#include <hip/hip_runtime.h>
#include <stdint.h>
#include <stddef.h>

typedef __bf16 bf16_t;
typedef __bf16 bf16x8 __attribute__((ext_vector_type(8)));
typedef __bf16 bf16x4 __attribute__((ext_vector_type(4)));
typedef float  f32x4  __attribute__((ext_vector_type(4)));

// ---------------------------------------------------------------------------
// Kernel 1: per-block partial sums of |W|  (W is 1024x1024 fp32)
// ---------------------------------------------------------------------------
__global__ __launch_bounds__(256)
void k_abssum(const float* __restrict__ W, float* __restrict__ partials) {
    const int t = threadIdx.x;
    const int b = blockIdx.x;
    const f32x4* W4 = reinterpret_cast<const f32x4*>(W);
    float s = 0.f;
    const int base = b * 1024 + t;           // float4 index
#pragma unroll
    for (int i = 0; i < 4; ++i) {
        f32x4 v = W4[base + i * 256];
        s += fabsf(v[0]) + fabsf(v[1]) + fabsf(v[2]) + fabsf(v[3]);
    }
#pragma unroll
    for (int off = 32; off > 0; off >>= 1) s += __shfl_down(s, off);
    __shared__ float red[4];
    if ((t & 63) == 0) red[t >> 6] = s;
    __syncthreads();
    if (t == 0) partials[b] = red[0] + red[1] + red[2] + red[3];
}

// ---------------------------------------------------------------------------
// Kernel 2: combine partials -> scale; ternarize W into fragment-tiled layout:
//   T[bn(8)][kt(16)][kq8(8)][nn(128)][8 bf16]   (2 MB total)
// so the GEMM's global_load_lds is a linear 16 KB tile copy and the b128
// fragment reads are conflict-free.
// 512 blocks x 256 threads; each thread handles 8 consecutive k of one n.
// ---------------------------------------------------------------------------
__global__ __launch_bounds__(256)
void k_ternarize(const float* __restrict__ W, const float* __restrict__ partials,
                 bf16_t* __restrict__ T, float* __restrict__ scale_out) {
    const int t = threadIdx.x;
    float s = partials[t];
#pragma unroll
    for (int off = 32; off > 0; off >>= 1) s += __shfl_down(s, off);
    __shared__ float red[4];
    if ((t & 63) == 0) red[t >> 6] = s;
    __syncthreads();
    const float total = red[0] + red[1] + red[2] + red[3];
    const float scale = total * (1.0f / 1048576.0f);
    const float inv   = 1.0f / fmaxf(scale, 1e-8f);

    const int c  = blockIdx.x * 256 + t;     // chunk id, 131072 total
    const int n  = c >> 7;                   // 0..1023 (row of W)
    const int k  = (c & 127) * 8;            // 0..1016
    const float* wp = W + (size_t)n * 1024 + k;
    f32x4 w0 = *reinterpret_cast<const f32x4*>(wp);
    f32x4 w1 = *reinterpret_cast<const f32x4*>(wp + 4);
    bf16x8 q;
#pragma unroll
    for (int j = 0; j < 4; ++j) {
        float q0 = fminf(1.f, fmaxf(-1.f, rintf(w0[j] * inv)));
        float q1 = fminf(1.f, fmaxf(-1.f, rintf(w1[j] * inv)));
        q[j]     = (bf16_t)q0;
        q[4 + j] = (bf16_t)q1;
    }
    const int bn = n >> 7, nn = n & 127;
    const int kt = k >> 6, kq8 = (k & 63) >> 3;
    const size_t chunk = ((size_t)(bn * 16 + kt) * 8 + kq8) * 128 + nn;
    reinterpret_cast<bf16x8*>(T)[chunk] = q;
    if (c == 0) scale_out[0] = scale;
}

// ---------------------------------------------------------------------------
// Kernel 3: GEMM  out[m][n] = scale * sum_k x[m][k]*t[n][k] + bias[n]
// M=65536, N=1024, K=1024.  BM=BN=128, BK=64, 256 threads (4 waves, 2x2).
// A: reg-staged fp32->bf16 into XOR-swizzled [kq8][m][8] LDS (2-way R/W).
// B: linear global_load_lds of pre-tiled fragments (conflict-free reads).
// 32 x mfma_f32_16x16x32_bf16 per wave per K-tile; 16 barrier-pairs total.
// ---------------------------------------------------------------------------
__global__ __launch_bounds__(256, 3)
void k_gemm(const float* __restrict__ X, const bf16_t* __restrict__ T,
            const float* __restrict__ bias, const float* __restrict__ scale_p,
            float* __restrict__ Out) {
    __shared__ bf16_t As[8192];   // [kq8(8)][m(128)][8], chunks XOR'd by (m+kq8)&7
    __shared__ bf16_t Bs[8192];   // [kq8(8)][n(128)][8], linear copy of T tile

    const int tid  = threadIdx.x;
    const int lane = tid & 63;
    const int w    = tid >> 6;
    const int wr   = w >> 1;
    const int wc   = w & 1;
    const int lq   = lane >> 4;
    const int rl   = lane & 15;

    // XCD-aware bijective swizzle (4096 blocks, 8 XCDs): 8 consecutive sids
    // within an XCD share one A-panel.
    const int bid  = blockIdx.x;
    const int sid  = (bid & 7) * 512 + (bid >> 3);
    const int bn   = sid & 7;
    const int bm   = sid >> 3;
    const int row0 = bm * 128;
    const int col0 = bn * 128;

    // ---- A staging: thread owns (m = tid>>3 (+32h), kq8 = tid&7)
    const int am  = tid >> 3;
    const int akq = tid & 7;
    const float* xA = X + (size_t)(row0 + am) * 1024 + akq * 8;
    int awoff[4];
#pragma unroll
    for (int h = 0; h < 4; ++h) {
        const int m = am + 32 * h;
        awoff[h] = (akq * 128 + (m & ~7) + ((m + akq) & 7)) * 16;   // bytes
    }

    // ---- B staging: 16 x 1024B issues per tile; wave w does 4
    const bf16_t* gB = T + (size_t)bn * 16 * 8192 + (size_t)(w * 4) * 512 + (size_t)lane * 8;
    bf16_t* ldsB = Bs + (size_t)(w * 4) * 512;

    // ---- fragment read byte-offsets (loop-invariant)
    int aoff[2][4], boff[2][4];
#pragma unroll
    for (int kk = 0; kk < 2; ++kk) {
        const int kq8 = kk * 4 + lq;
#pragma unroll
        for (int i = 0; i < 4; ++i) {
            const int m = wr * 64 + i * 16 + rl;
            aoff[kk][i] = (kq8 * 128 + (m & ~7) + ((m + kq8) & 7)) * 16;
            boff[kk][i] = (kq8 * 128 + wc * 64 + i * 16 + rl) * 16;
        }
    }

    f32x4 acc[4][4];
    {
        f32x4 z = {0.f, 0.f, 0.f, 0.f};
#pragma unroll
        for (int i = 0; i < 4; ++i)
#pragma unroll
            for (int j = 0; j < 4; ++j) acc[i][j] = z;
    }

    f32x4 a0[4], a1[4];
#define LOAD_A(kt)                                                          \
    {                                                                       \
        _Pragma("unroll")                                                   \
        for (int h = 0; h < 4; ++h) {                                       \
            const float* p = xA + (size_t)h * 32 * 1024 + (kt) * 64;        \
            a0[h] = *(const f32x4*)(p);                                     \
            a1[h] = *(const f32x4*)(p + 4);                                 \
        }                                                                   \
    }

    LOAD_A(0);

    for (int kt = 0; kt < 16; ++kt) {
        __syncthreads();   // previous tile's compute done
        // --- B stage first: 4 linear global_load_lds issues in flight
#pragma unroll
        for (int i = 0; i < 4; ++i)
            __builtin_amdgcn_global_load_lds(
                (const __attribute__((address_space(1))) void*)(gB + (size_t)kt * 8192 + i * 512),
                (__attribute__((address_space(3))) void*)(ldsB + i * 512), 16, 0, 0);
        // --- A stage: convert fp32->bf16, conflict-free ds_write_b128
#pragma unroll
        for (int h = 0; h < 4; ++h) {
            bf16x8 v;
#pragma unroll
            for (int j = 0; j < 4; ++j) {
                v[j]     = (bf16_t)a0[h][j];
                v[4 + j] = (bf16_t)a1[h][j];
            }
            *reinterpret_cast<bf16x8*>((char*)As + awoff[h]) = v;
        }
        __syncthreads();   // tile ready

        if (kt + 1 < 16) LOAD_A(kt + 1);   // prefetch next A (drains by next top barrier)

#pragma unroll
        for (int kk = 0; kk < 2; ++kk) {
            bf16x8 af[4], bfr[4];
#pragma unroll
            for (int i = 0; i < 4; ++i) {
                af[i]  = *reinterpret_cast<const bf16x8*>((const char*)As + aoff[kk][i]);
                bfr[i] = *reinterpret_cast<const bf16x8*>((const char*)Bs + boff[kk][i]);
            }
#pragma unroll
            for (int mi = 0; mi < 4; ++mi)
#pragma unroll
                for (int ni = 0; ni < 4; ++ni)
                    acc[mi][ni] = __builtin_amdgcn_mfma_f32_16x16x32_bf16(
                        af[mi], bfr[ni], acc[mi][ni], 0, 0, 0);
        }
    }

    // --- epilogue: out = acc*scale + bias
    const float scale = scale_p[0];
    float bv[4];
#pragma unroll
    for (int ni = 0; ni < 4; ++ni)
        bv[ni] = bias[col0 + wc * 64 + ni * 16 + rl];
#pragma unroll
    for (int mi = 0; mi < 4; ++mi) {
        const int gm0 = row0 + wr * 64 + mi * 16 + lq * 4;
#pragma unroll
        for (int ni = 0; ni < 4; ++ni) {
            const int gn = col0 + wc * 64 + ni * 16 + rl;
#pragma unroll
            for (int j = 0; j < 4; ++j)
                Out[(size_t)(gm0 + j) * 1024 + gn] = acc[mi][ni][j] * scale + bv[ni];
        }
    }
#undef LOAD_A
}

// ---------------------------------------------------------------------------
extern "C" void kernel_launch(void* const* d_in, const int* in_sizes, int n_in,
                              void* d_out, int out_size, void* d_ws, size_t ws_size,
                              hipStream_t stream) {
    const float* x    = (const float*)d_in[0];   // [8,8192,1024] fp32
    const float* W    = (const float*)d_in[1];   // [1024,1024]   fp32
    const float* bias = (const float*)d_in[2];   // [1024]        fp32
    float* out = (float*)d_out;

    float*  ws_part  = (float*)d_ws;             // 256 floats
    float*  ws_scale = ws_part + 256;            // 1 float
    bf16_t* ws_T     = (bf16_t*)(ws_part + 512); // 1M bf16 = 2 MB (16B aligned)

    hipLaunchKernelGGL(k_abssum,    dim3(256), dim3(256), 0, stream, W, ws_part);
    hipLaunchKernelGGL(k_ternarize, dim3(512), dim3(256), 0, stream, W, ws_part, ws_T, ws_scale);
    hipLaunchKernelGGL(k_gemm,      dim3(4096), dim3(256), 0, stream, x, ws_T, bias, ws_scale, out);
}